// Round 10
// baseline (6646.144 us; speedup 1.0000x reference)
//
#include <hip/hip_runtime.h>
#include <hip/hip_fp16.h>
#include <math.h>

#define TT 833          // output timesteps
#define GDIM 1024       // 4*H gates

typedef _Float16 f16x8 __attribute__((ext_vector_type(8)));
typedef float    f32x4 __attribute__((ext_vector_type(4)));

__device__ __forceinline__ float sigm(float x){ return 1.f/(1.f+expf(-x)); }

// ---------------- level smoothing scan ----------------
__global__ void levels_k(const float* __restrict__ train, const float* __restrict__ ism,
                         float* __restrict__ levs){
  int b = threadIdx.x;
  if (b >= 32) return;
  float a = 1.f/(1.f+expf(-ism[0]));
  const float* tr = train + b*1024;
  float* lv = levs + b*1024;
  float lev = fmaxf(tr[0], 0.1f);
  lv[0] = lev;
  for (int t = 1; t < 1024; ++t){
    lev = fmaxf(a*tr[t] + (1.f-a)*lev, 0.1f);
    lv[t] = lev;
  }
}

// ---------------- normalized input windows x0[t*32+b][168] ----------------
__global__ void win_x_k(const float* __restrict__ train, const float* __restrict__ levs,
                        float* __restrict__ x0){
  int idx = blockIdx.x*256 + threadIdx.x;   // exactly 833*32*168
  int i = idx % 168;
  int r = idx / 168;       // t*32+b
  int b = r & 31;
  int t = r >> 5;
  x0[idx] = train[b*1024 + t + i] / levs[b*1024 + t + 167];
}

// ---------------- out_win -> d_out second half ----------------
__global__ void win_out_k(const float* __restrict__ train, const float* __restrict__ levs,
                          float* __restrict__ ow){
  int idx = blockIdx.x*256 + threadIdx.x;   // exactly 833*32*24
  int o = idx % 24;
  int r = idx / 24;
  int b = r & 31;
  int t = r >> 5;
  ow[idx] = train[b*1024 + 168 + t + o] / levs[b*1024 + t + 167];
}

// ---------------- quantize whh[1024][256] fp32 -> int8 wq[k16][1024] (+ per-row scale) ----
// wq[k16][g] = 16 consecutive int8 of row g; sc[g] = rowmax/127.
__global__ void packq_k(const float* __restrict__ w, uint4* __restrict__ wq,
                        float* __restrict__ sc){
  int g = blockIdx.x*256 + threadIdx.x;   // 1024 rows over 4 blocks
  if (g >= 1024) return;
  const float* row = w + (size_t)g*256;
  float amax = 0.f;
  for (int k = 0; k < 256; ++k) amax = fmaxf(amax, fabsf(row[k]));
  amax = fmaxf(amax, 1e-20f);
  float s = amax/127.f, inv = 127.f/amax;
  sc[g] = s;
  for (int k16 = 0; k16 < 16; ++k16){
    union { uint4 u; signed char b[16]; } r;
    #pragma unroll
    for (int j = 0; j < 16; ++j){
      float q = rintf(row[k16*16 + j]*inv);
      q = fminf(fmaxf(q, -127.f), 127.f);
      r.b[j] = (signed char)q;
    }
    wq[(size_t)k16*1024 + g] = r.u;
  }
}

// ---------------- MFMA fp16 GEMM: C[m][n] = A[map(m)][:K] . W[n][:K] + b1 (+b2), opt tanh ----
// 128x128 tile, 4 waves (2x2), mfma_f32_16x16x32_f16, 4x4 frags/wave, BK=32.
__global__ __launch_bounds__(256) void proj_mfma(
    const float* __restrict__ A, const float* __restrict__ W,
    const float* __restrict__ b1, const float* __restrict__ b2,
    float* __restrict__ C, int Mout, int K, int N, int dil, int act)
{
  __shared__ _Float16 As[128*40];
  __shared__ _Float16 Bs[128*40];
  const int tid = threadIdx.x;
  const int lane = tid & 63;
  const int w = tid >> 6, wr = w >> 1, wc = w & 1;
  const int m0 = blockIdx.y << 7, n0 = blockIdx.x << 7;

  const int rowA = tid >> 1;
  int srcrow;
  {
    int m = m0 + rowA;
    if (dil == 0) srcrow = (m < Mout) ? m : -1;
    else {
      int rows = dil << 5;
      int j = m / rows;
      int q = m - j*rows;
      int t = j*dil + (q >> 5);
      srcrow = (t < TT) ? ((t << 5) + (q & 31)) : -1;
    }
  }
  const int halfsel = tid & 1;
  const int nrow = n0 + rowA;

  f32x4 acc[4][4];
  #pragma unroll
  for (int i = 0; i < 4; ++i)
    #pragma unroll
    for (int j = 0; j < 4; ++j) acc[i][j] = (f32x4){0.f,0.f,0.f,0.f};

  const int nkt = (K + 31) >> 5;
  for (int kt = 0; kt < nkt; ++kt){
    const int k0 = (kt << 5) + halfsel*16;
    {
      union { uint4 u[2]; _Float16 h[16]; } tmp;
      if (srcrow >= 0 && k0 + 16 <= K){
        const float* s = A + (size_t)srcrow*K + k0;
        #pragma unroll
        for (int j = 0; j < 4; ++j){
          float4 v = *reinterpret_cast<const float4*>(s + j*4);
          tmp.h[j*4+0]=(_Float16)v.x; tmp.h[j*4+1]=(_Float16)v.y;
          tmp.h[j*4+2]=(_Float16)v.z; tmp.h[j*4+3]=(_Float16)v.w;
        }
      } else {
        const float* s = (srcrow >= 0) ? A + (size_t)srcrow*K : nullptr;
        #pragma unroll
        for (int j = 0; j < 16; ++j){
          int kk = k0 + j;
          tmp.h[j] = (s && kk < K) ? (_Float16)s[kk] : (_Float16)0.f;
        }
      }
      uint4* dst = reinterpret_cast<uint4*>(&As[rowA*40 + halfsel*16]);
      dst[0] = tmp.u[0]; dst[1] = tmp.u[1];
    }
    {
      union { uint4 u[2]; _Float16 h[16]; } tmp;
      if (k0 + 16 <= K){
        const float* s = W + (size_t)nrow*K + k0;
        #pragma unroll
        for (int j = 0; j < 4; ++j){
          float4 v = *reinterpret_cast<const float4*>(s + j*4);
          tmp.h[j*4+0]=(_Float16)v.x; tmp.h[j*4+1]=(_Float16)v.y;
          tmp.h[j*4+2]=(_Float16)v.z; tmp.h[j*4+3]=(_Float16)v.w;
        }
      } else {
        const float* s = W + (size_t)nrow*K;
        #pragma unroll
        for (int j = 0; j < 16; ++j){
          int kk = k0 + j;
          tmp.h[j] = (kk < K) ? (_Float16)s[kk] : (_Float16)0.f;
        }
      }
      uint4* dst = reinterpret_cast<uint4*>(&Bs[rowA*40 + halfsel*16]);
      dst[0] = tmp.u[0]; dst[1] = tmp.u[1];
    }
    __syncthreads();
    {
      const int kg = lane >> 4, r16 = lane & 15;
      f16x8 af[4], bf[4];
      #pragma unroll
      for (int mi = 0; mi < 4; ++mi)
        af[mi] = *reinterpret_cast<const f16x8*>(&As[(wr*64 + mi*16 + r16)*40 + kg*8]);
      #pragma unroll
      for (int nj = 0; nj < 4; ++nj)
        bf[nj] = *reinterpret_cast<const f16x8*>(&Bs[(wc*64 + nj*16 + r16)*40 + kg*8]);
      #pragma unroll
      for (int mi = 0; mi < 4; ++mi)
        #pragma unroll
        for (int nj = 0; nj < 4; ++nj)
          acc[mi][nj] = __builtin_amdgcn_mfma_f32_16x16x32_f16(af[mi], bf[nj], acc[mi][nj], 0, 0, 0);
    }
    __syncthreads();
  }
  #pragma unroll
  for (int mi = 0; mi < 4; ++mi){
    #pragma unroll
    for (int p = 0; p < 4; ++p){
      int mrow = m0 + wr*64 + mi*16 + (lane >> 4)*4 + p;
      if (mrow >= Mout) continue;
      #pragma unroll
      for (int nj = 0; nj < 4; ++nj){
        int ncol = n0 + wc*64 + nj*16 + (lane & 15);
        float v = acc[mi][nj][p] + b1[ncol] + (b2 ? b2[ncol] : 0.f);
        if (act) v = tanhf(v);
        C[(size_t)mrow*N + ncol] = v;
      }
    }
  }
}

// ---------------- streamed int8-weight dilated-LSTM recurrence, 1024 threads ----------------
// r8 known-good shape (pure streaming, rolled loop, no pinning — r5-r7 lessons), payload
// halved to int8: 16 x uint4 per thread per step = 256KB/WG/step from L2.
// Thread t owns gate row t; per-row scale applied once per step.
template<int NR>
__global__ __launch_bounds__(1024) void srecq_k(
    const uint4* __restrict__ wq, const float* __restrict__ scale,
    const float* __restrict__ Gin,
    float* __restrict__ out, const float* __restrict__ res,
    int nsteps, int d, int rowsTotal)
{
  __shared__ float4 hh[NR][64];      // h[256] per row as float4
  __shared__ float psum[NR][1024];
  __shared__ float cst[NR][256];
  const int tid = threadIdx.x;
  const int q0 = blockIdx.x*NR;
  const float sg = scale[tid];
  for (int e = tid; e < NR*64; e += 1024) (&hh[0][0])[e] = make_float4(0.f,0.f,0.f,0.f);
  for (int e = tid; e < NR*256; e += 1024) (&cst[0][0])[e] = 0.f;
  __syncthreads();

  for (int step = 0; step < nsteps; ++step){
    float gin[NR];
    const float* gbase = Gin + ((size_t)step*rowsTotal + q0)*GDIM;
    #pragma unroll
    for (int rr = 0; rr < NR; ++rr) gin[rr] = gbase[rr*GDIM + tid];
    float acc[NR];
    #pragma unroll
    for (int rr = 0; rr < NR; ++rr) acc[rr] = 0.f;

    #pragma unroll 4
    for (int k16 = 0; k16 < 16; ++k16){
      uint4 w = wq[(size_t)k16*1024 + tid];
      float wf[16];
      {
        int v;
        v = (int)w.x;
        wf[0]=(float)((v<<24)>>24); wf[1]=(float)((v<<16)>>24);
        wf[2]=(float)((v<<8)>>24);  wf[3]=(float)(v>>24);
        v = (int)w.y;
        wf[4]=(float)((v<<24)>>24); wf[5]=(float)((v<<16)>>24);
        wf[6]=(float)((v<<8)>>24);  wf[7]=(float)(v>>24);
        v = (int)w.z;
        wf[8]=(float)((v<<24)>>24);  wf[9]=(float)((v<<16)>>24);
        wf[10]=(float)((v<<8)>>24);  wf[11]=(float)(v>>24);
        v = (int)w.w;
        wf[12]=(float)((v<<24)>>24); wf[13]=(float)((v<<16)>>24);
        wf[14]=(float)((v<<8)>>24);  wf[15]=(float)(v>>24);
      }
      #pragma unroll
      for (int rr = 0; rr < NR; ++rr){
        float4 h0_ = hh[rr][4*k16 + 0];
        float4 h1_ = hh[rr][4*k16 + 1];
        float4 h2_ = hh[rr][4*k16 + 2];
        float4 h3_ = hh[rr][4*k16 + 3];
        acc[rr] = fmaf(wf[0],  h0_.x, acc[rr]);
        acc[rr] = fmaf(wf[1],  h0_.y, acc[rr]);
        acc[rr] = fmaf(wf[2],  h0_.z, acc[rr]);
        acc[rr] = fmaf(wf[3],  h0_.w, acc[rr]);
        acc[rr] = fmaf(wf[4],  h1_.x, acc[rr]);
        acc[rr] = fmaf(wf[5],  h1_.y, acc[rr]);
        acc[rr] = fmaf(wf[6],  h1_.z, acc[rr]);
        acc[rr] = fmaf(wf[7],  h1_.w, acc[rr]);
        acc[rr] = fmaf(wf[8],  h2_.x, acc[rr]);
        acc[rr] = fmaf(wf[9],  h2_.y, acc[rr]);
        acc[rr] = fmaf(wf[10], h2_.z, acc[rr]);
        acc[rr] = fmaf(wf[11], h2_.w, acc[rr]);
        acc[rr] = fmaf(wf[12], h3_.x, acc[rr]);
        acc[rr] = fmaf(wf[13], h3_.y, acc[rr]);
        acc[rr] = fmaf(wf[14], h3_.z, acc[rr]);
        acc[rr] = fmaf(wf[15], h3_.w, acc[rr]);
      }
    }
    #pragma unroll
    for (int rr = 0; rr < NR; ++rr) psum[rr][tid] = fmaf(acc[rr], sg, gin[rr]);
    __syncthreads();
    for (int e = tid; e < NR*256; e += 1024){
      int rr = e >> 8, j = e & 255;
      float iv = psum[rr][j];
      float fv = psum[rr][j + 256];
      float gv = psum[rr][j + 512];
      float ov = psum[rr][j + 768];
      float c = cst[rr][j];
      c = sigm(fv)*c + sigm(iv)*tanhf(gv);
      float h = sigm(ov)*tanhf(c);
      cst[rr][j] = c;
      reinterpret_cast<float*>(&hh[rr][0])[j] = h;
      int q = q0 + rr;
      int tg = step*d + (q >> 5);
      if (tg < TT){
        size_t oi = ((size_t)tg*32 + (q & 31))*256 + j;
        out[oi] = res ? (h + res[oi]) : h;
      }
    }
    __syncthreads();
  }
}

// ---------------- scoring head: pred[m][24] = xt[m][:] . sc_w[n][:] + sc_b ----------------
__global__ __launch_bounds__(256) void sc_head(const float* __restrict__ xt, const float* __restrict__ w,
                        const float* __restrict__ bias, float* __restrict__ outp, int M){
  __shared__ float arow[8][256];
  int m0 = blockIdx.x << 3;
  int tid = threadIdx.x;
  #pragma unroll
  for (int i = 0; i < 8; ++i){
    int e = tid + (i << 8);
    int r = e >> 8, k = e & 255;
    arow[r][k] = (m0 + r < M) ? xt[(size_t)(m0 + r)*256 + k] : 0.f;
  }
  __syncthreads();
  int r = tid >> 5, n = tid & 31;
  if (n < 24 && (m0 + r) < M){
    float acc = bias[n];
    const float* wr = w + n*256;
    #pragma unroll 8
    for (int k = 0; k < 256; ++k) acc = fmaf(arow[r][k], wr[k], acc);
    outp[(size_t)(m0 + r)*24 + n] = acc;
  }
}

extern "C" void kernel_launch(void* const* d_in, const int* in_sizes, int n_in,
                              void* d_out, int out_size, void* d_ws, size_t ws_size,
                              hipStream_t stream){
  const float* train = (const float*)d_in[0];
  const float* ism   = (const float*)d_in[4];
  const float* wih[4] = {(const float*)d_in[5], (const float*)d_in[9], (const float*)d_in[13], (const float*)d_in[17]};
  const float* whh[4] = {(const float*)d_in[6], (const float*)d_in[10], (const float*)d_in[14], (const float*)d_in[18]};
  const float* bih[4] = {(const float*)d_in[7], (const float*)d_in[11], (const float*)d_in[15], (const float*)d_in[19]};
  const float* bhh[4] = {(const float*)d_in[8], (const float*)d_in[12], (const float*)d_in[16], (const float*)d_in[20]};
  const float* nl_w = (const float*)d_in[21];
  const float* nl_b = (const float*)d_in[22];
  const float* sc_w = (const float*)d_in[23];
  const float* sc_b = (const float*)d_in[24];
  float* out = (float*)d_out;

  float* ws = (float*)d_ws;
  size_t off = 0;
  float* levs = ws + off;   off += 32768;
  uint4* wqk[4];
  for (int l = 0; l < 4; ++l){ wqk[l] = (uint4*)(ws + off); off += 65536; }   // 256KB each
  float* sck[4];
  for (int l = 0; l < 4; ++l){ sck[l] = ws + off; off += 1024; }
  float* x0 = ws + off;     off += (size_t)26656*168;
  float* G  = ws + off;     off += (size_t)28672*1024;
  float* h0 = ws + off;     off += (size_t)26656*256;
  float* h1 = ws + off;     off += (size_t)26656*256;
  float* h2 = ws + off;     off += (size_t)26656*256;
  (void)ws_size; (void)in_sizes; (void)n_in; (void)out_size;

  levels_k<<<1, 64, 0, stream>>>(train, ism, levs);
  win_x_k<<<17493, 256, 0, stream>>>(train, levs, x0);
  win_out_k<<<2499, 256, 0, stream>>>(train, levs, out + 639744);
  for (int l = 0; l < 4; ++l)
    packq_k<<<4, 256, 0, stream>>>(whh[l], wqk[l], sck[l]);

  // layer 0 (d=1): 833 steps, 32 rows -> 32 WGs x 1 row
  proj_mfma<<<dim3(8,209), 256, 0, stream>>>(x0, wih[0], bih[0], bhh[0], G, 26656, 168, 1024, 0, 0);
  srecq_k<1><<<32, 1024, 0, stream>>>(wqk[0], sck[0], G, h0, nullptr, 833, 1, 32);
  // layer 1 (d=4): 209 steps, 128 rows -> 128 WGs x 1 row
  proj_mfma<<<dim3(8,209), 256, 0, stream>>>(h0, wih[1], bih[1], bhh[1], G, 26752, 256, 1024, 4, 0);
  srecq_k<1><<<128, 1024, 0, stream>>>(wqk[1], sck[1], G, h1, nullptr, 209, 4, 128);
  // layer 2 (d=16): 53 steps, 512 rows -> 256 WGs x 2 rows
  proj_mfma<<<dim3(8,212), 256, 0, stream>>>(h1, wih[2], bih[2], bhh[2], G, 27136, 256, 1024, 16, 0);
  srecq_k<2><<<256, 1024, 0, stream>>>(wqk[2], sck[2], G, h2, nullptr, 53, 16, 512);
  // layer 3 (d=64): 14 steps, 2048 rows -> 256 WGs x 8 rows; residual h1; out overwrites h2
  proj_mfma<<<dim3(8,224), 256, 0, stream>>>(h2, wih[3], bih[3], bhh[3], G, 28672, 256, 1024, 64, 0);
  srecq_k<8><<<256, 1024, 0, stream>>>(wqk[3], sck[3], G, h2, h1, 14, 64, 2048);
  // nonlinear dense: xt = tanh(xf @ nl_w.T + nl_b)  (reuse h0)
  proj_mfma<<<dim3(2,209), 256, 0, stream>>>(h2, nl_w, nl_b, nullptr, h0, 26656, 256, 256, 0, 1);
  // scoring head -> pred (first half of d_out)
  sc_head<<<3332, 256, 0, stream>>>(h0, sc_w, sc_b, out, 26656);
}

// Round 11
// 3594.392 us; speedup vs baseline: 1.8490x; 1.8490x over previous
//
#include <hip/hip_runtime.h>
#include <hip/hip_fp16.h>
#include <math.h>

#define TT 833          // output timesteps
#define GDIM 1024       // 4*H gates

typedef _Float16 f16x8 __attribute__((ext_vector_type(8)));
typedef float    f32x4 __attribute__((ext_vector_type(4)));

__device__ __forceinline__ float sigm(float x){ return 1.f/(1.f+expf(-x)); }

#if __has_builtin(__builtin_amdgcn_sdot4)
__device__ __forceinline__ int sdot4(unsigned a, unsigned b, int c){
  return __builtin_amdgcn_sdot4((int)a, (int)b, c, false);
}
#else
__device__ __forceinline__ int sdot4(unsigned a, unsigned b, int c){
  int ai = (int)a, bi = (int)b;
  c += ((ai<<24)>>24)*((bi<<24)>>24);
  c += ((ai<<16)>>24)*((bi<<16)>>24);
  c += ((ai<<8)>>24)*((bi<<8)>>24);
  c += (ai>>24)*(bi>>24);
  return c;
}
#endif

// ---------------- level smoothing scan ----------------
__global__ void levels_k(const float* __restrict__ train, const float* __restrict__ ism,
                         float* __restrict__ levs){
  int b = threadIdx.x;
  if (b >= 32) return;
  float a = 1.f/(1.f+expf(-ism[0]));
  const float* tr = train + b*1024;
  float* lv = levs + b*1024;
  float lev = fmaxf(tr[0], 0.1f);
  lv[0] = lev;
  for (int t = 1; t < 1024; ++t){
    lev = fmaxf(a*tr[t] + (1.f-a)*lev, 0.1f);
    lv[t] = lev;
  }
}

// ---------------- normalized input windows x0[t*32+b][168] ----------------
__global__ void win_x_k(const float* __restrict__ train, const float* __restrict__ levs,
                        float* __restrict__ x0){
  int idx = blockIdx.x*256 + threadIdx.x;   // exactly 833*32*168
  int i = idx % 168;
  int r = idx / 168;       // t*32+b
  int b = r & 31;
  int t = r >> 5;
  x0[idx] = train[b*1024 + t + i] / levs[b*1024 + t + 167];
}

// ---------------- out_win -> d_out second half ----------------
__global__ void win_out_k(const float* __restrict__ train, const float* __restrict__ levs,
                          float* __restrict__ ow){
  int idx = blockIdx.x*256 + threadIdx.x;   // exactly 833*32*24
  int o = idx % 24;
  int r = idx / 24;
  int b = r & 31;
  int t = r >> 5;
  ow[idx] = train[b*1024 + 168 + t + o] / levs[b*1024 + t + 167];
}

// ---------------- quantize whh[1024][256] fp32 -> int8 wq[k16][1024] (+ per-row scale) ----
// wq[k16][g] = 16 consecutive int8 of row g; sc[g] = rowmax/127.
__global__ void packq_k(const float* __restrict__ w, uint4* __restrict__ wq,
                        float* __restrict__ sc){
  int g = blockIdx.x*256 + threadIdx.x;   // 1024 rows over 4 blocks
  if (g >= 1024) return;
  const float* row = w + (size_t)g*256;
  float amax = 0.f;
  for (int k = 0; k < 256; ++k) amax = fmaxf(amax, fabsf(row[k]));
  amax = fmaxf(amax, 1e-20f);
  float s = amax/127.f, inv = 127.f/amax;
  sc[g] = s;
  for (int k16 = 0; k16 < 16; ++k16){
    union { uint4 u; signed char b[16]; } r;
    #pragma unroll
    for (int j = 0; j < 16; ++j){
      float q = rintf(row[k16*16 + j]*inv);
      q = fminf(fmaxf(q, -127.f), 127.f);
      r.b[j] = (signed char)q;
    }
    wq[(size_t)k16*1024 + g] = r.u;
  }
}

// ---------------- MFMA fp16 GEMM: C[m][n] = A[map(m)][:K] . W[n][:K] + b1 (+b2), opt tanh ----
// 128x128 tile, 4 waves (2x2), mfma_f32_16x16x32_f16, 4x4 frags/wave, BK=32.
__global__ __launch_bounds__(256) void proj_mfma(
    const float* __restrict__ A, const float* __restrict__ W,
    const float* __restrict__ b1, const float* __restrict__ b2,
    float* __restrict__ C, int Mout, int K, int N, int dil, int act)
{
  __shared__ _Float16 As[128*40];
  __shared__ _Float16 Bs[128*40];
  const int tid = threadIdx.x;
  const int lane = tid & 63;
  const int w = tid >> 6, wr = w >> 1, wc = w & 1;
  const int m0 = blockIdx.y << 7, n0 = blockIdx.x << 7;

  const int rowA = tid >> 1;
  int srcrow;
  {
    int m = m0 + rowA;
    if (dil == 0) srcrow = (m < Mout) ? m : -1;
    else {
      int rows = dil << 5;
      int j = m / rows;
      int q = m - j*rows;
      int t = j*dil + (q >> 5);
      srcrow = (t < TT) ? ((t << 5) + (q & 31)) : -1;
    }
  }
  const int halfsel = tid & 1;
  const int nrow = n0 + rowA;

  f32x4 acc[4][4];
  #pragma unroll
  for (int i = 0; i < 4; ++i)
    #pragma unroll
    for (int j = 0; j < 4; ++j) acc[i][j] = (f32x4){0.f,0.f,0.f,0.f};

  const int nkt = (K + 31) >> 5;
  for (int kt = 0; kt < nkt; ++kt){
    const int k0 = (kt << 5) + halfsel*16;
    {
      union { uint4 u[2]; _Float16 h[16]; } tmp;
      if (srcrow >= 0 && k0 + 16 <= K){
        const float* s = A + (size_t)srcrow*K + k0;
        #pragma unroll
        for (int j = 0; j < 4; ++j){
          float4 v = *reinterpret_cast<const float4*>(s + j*4);
          tmp.h[j*4+0]=(_Float16)v.x; tmp.h[j*4+1]=(_Float16)v.y;
          tmp.h[j*4+2]=(_Float16)v.z; tmp.h[j*4+3]=(_Float16)v.w;
        }
      } else {
        const float* s = (srcrow >= 0) ? A + (size_t)srcrow*K : nullptr;
        #pragma unroll
        for (int j = 0; j < 16; ++j){
          int kk = k0 + j;
          tmp.h[j] = (s && kk < K) ? (_Float16)s[kk] : (_Float16)0.f;
        }
      }
      uint4* dst = reinterpret_cast<uint4*>(&As[rowA*40 + halfsel*16]);
      dst[0] = tmp.u[0]; dst[1] = tmp.u[1];
    }
    {
      union { uint4 u[2]; _Float16 h[16]; } tmp;
      if (k0 + 16 <= K){
        const float* s = W + (size_t)nrow*K + k0;
        #pragma unroll
        for (int j = 0; j < 4; ++j){
          float4 v = *reinterpret_cast<const float4*>(s + j*4);
          tmp.h[j*4+0]=(_Float16)v.x; tmp.h[j*4+1]=(_Float16)v.y;
          tmp.h[j*4+2]=(_Float16)v.z; tmp.h[j*4+3]=(_Float16)v.w;
        }
      } else {
        const float* s = W + (size_t)nrow*K;
        #pragma unroll
        for (int j = 0; j < 16; ++j){
          int kk = k0 + j;
          tmp.h[j] = (kk < K) ? (_Float16)s[kk] : (_Float16)0.f;
        }
      }
      uint4* dst = reinterpret_cast<uint4*>(&Bs[rowA*40 + halfsel*16]);
      dst[0] = tmp.u[0]; dst[1] = tmp.u[1];
    }
    __syncthreads();
    {
      const int kg = lane >> 4, r16 = lane & 15;
      f16x8 af[4], bf[4];
      #pragma unroll
      for (int mi = 0; mi < 4; ++mi)
        af[mi] = *reinterpret_cast<const f16x8*>(&As[(wr*64 + mi*16 + r16)*40 + kg*8]);
      #pragma unroll
      for (int nj = 0; nj < 4; ++nj)
        bf[nj] = *reinterpret_cast<const f16x8*>(&Bs[(wc*64 + nj*16 + r16)*40 + kg*8]);
      #pragma unroll
      for (int mi = 0; mi < 4; ++mi)
        #pragma unroll
        for (int nj = 0; nj < 4; ++nj)
          acc[mi][nj] = __builtin_amdgcn_mfma_f32_16x16x32_f16(af[mi], bf[nj], acc[mi][nj], 0, 0, 0);
    }
    __syncthreads();
  }
  #pragma unroll
  for (int mi = 0; mi < 4; ++mi){
    #pragma unroll
    for (int p = 0; p < 4; ++p){
      int mrow = m0 + wr*64 + mi*16 + (lane >> 4)*4 + p;
      if (mrow >= Mout) continue;
      #pragma unroll
      for (int nj = 0; nj < 4; ++nj){
        int ncol = n0 + wc*64 + nj*16 + (lane & 15);
        float v = acc[mi][nj][p] + b1[ncol] + (b2 ? b2[ncol] : 0.f);
        if (act) v = tanhf(v);
        C[(size_t)mrow*N + ncol] = v;
      }
    }
  }
}

// ---------------- int8xint8 sdot4 dilated-LSTM recurrence, 1024 threads ----------------
// r8 streaming shape (rolled loop, no pinning). Weights int8 (256KB/WG/step) AND
// h quantized to int8 per step (scale 127, exact since |h|<1). Matvec = v_dot4_i32_i8:
// 1 VALU op per 4 weights, no decode — cuts the r10 VALU bottleneck ~4x while keeping
// the halved byte stream. psum = acc_i32 * (s_row/127) + gin. Unquantized h goes to out.
template<int NR>
__global__ __launch_bounds__(1024) void srecq_k(
    const uint4* __restrict__ wq, const float* __restrict__ scale,
    const float* __restrict__ Gin,
    float* __restrict__ out, const float* __restrict__ res,
    int nsteps, int d, int rowsTotal)
{
  __shared__ unsigned int hq[NR][64];     // h int8-packed, 4 per uint
  __shared__ float psum[NR][1024];
  __shared__ float cst[NR][256];
  const int tid = threadIdx.x;
  const int q0 = blockIdx.x*NR;
  const float sg = scale[tid]*(1.f/127.f);
  for (int e = tid; e < NR*64; e += 1024) (&hq[0][0])[e] = 0u;
  for (int e = tid; e < NR*256; e += 1024) (&cst[0][0])[e] = 0.f;
  __syncthreads();

  for (int step = 0; step < nsteps; ++step){
    float gin[NR];
    const float* gbase = Gin + ((size_t)step*rowsTotal + q0)*GDIM;
    #pragma unroll
    for (int rr = 0; rr < NR; ++rr) gin[rr] = gbase[rr*GDIM + tid];
    int acc[NR];
    #pragma unroll
    for (int rr = 0; rr < NR; ++rr) acc[rr] = 0;

    #pragma unroll 4
    for (int k16 = 0; k16 < 16; ++k16){
      uint4 w = wq[(size_t)k16*1024 + tid];
      #pragma unroll
      for (int rr = 0; rr < NR; ++rr){
        uint4 h4 = *reinterpret_cast<const uint4*>(&hq[rr][4*k16]);
        acc[rr] = sdot4(w.x, h4.x, acc[rr]);
        acc[rr] = sdot4(w.y, h4.y, acc[rr]);
        acc[rr] = sdot4(w.z, h4.z, acc[rr]);
        acc[rr] = sdot4(w.w, h4.w, acc[rr]);
      }
    }
    #pragma unroll
    for (int rr = 0; rr < NR; ++rr) psum[rr][tid] = fmaf((float)acc[rr], sg, gin[rr]);
    __syncthreads();
    for (int e = tid; e < NR*256; e += 1024){
      int rr = e >> 8, j = e & 255;
      float iv = psum[rr][j];
      float fv = psum[rr][j + 256];
      float gv = psum[rr][j + 512];
      float ov = psum[rr][j + 768];
      float c = cst[rr][j];
      c = sigm(fv)*c + sigm(iv)*tanhf(gv);
      float h = sigm(ov)*tanhf(c);
      cst[rr][j] = c;
      int qh = (int)rintf(h*127.f);
      reinterpret_cast<signed char*>(&hq[rr][0])[j] = (signed char)qh;
      int q = q0 + rr;
      int tg = step*d + (q >> 5);
      if (tg < TT){
        size_t oi = ((size_t)tg*32 + (q & 31))*256 + j;
        out[oi] = res ? (h + res[oi]) : h;
      }
    }
    __syncthreads();
  }
}

// ---------------- scoring head: pred[m][24] = xt[m][:] . sc_w[n][:] + sc_b ----------------
__global__ __launch_bounds__(256) void sc_head(const float* __restrict__ xt, const float* __restrict__ w,
                        const float* __restrict__ bias, float* __restrict__ outp, int M){
  __shared__ float arow[8][256];
  int m0 = blockIdx.x << 3;
  int tid = threadIdx.x;
  #pragma unroll
  for (int i = 0; i < 8; ++i){
    int e = tid + (i << 8);
    int r = e >> 8, k = e & 255;
    arow[r][k] = (m0 + r < M) ? xt[(size_t)(m0 + r)*256 + k] : 0.f;
  }
  __syncthreads();
  int r = tid >> 5, n = tid & 31;
  if (n < 24 && (m0 + r) < M){
    float acc = bias[n];
    const float* wr = w + n*256;
    #pragma unroll 8
    for (int k = 0; k < 256; ++k) acc = fmaf(arow[r][k], wr[k], acc);
    outp[(size_t)(m0 + r)*24 + n] = acc;
  }
}

extern "C" void kernel_launch(void* const* d_in, const int* in_sizes, int n_in,
                              void* d_out, int out_size, void* d_ws, size_t ws_size,
                              hipStream_t stream){
  const float* train = (const float*)d_in[0];
  const float* ism   = (const float*)d_in[4];
  const float* wih[4] = {(const float*)d_in[5], (const float*)d_in[9], (const float*)d_in[13], (const float*)d_in[17]};
  const float* whh[4] = {(const float*)d_in[6], (const float*)d_in[10], (const float*)d_in[14], (const float*)d_in[18]};
  const float* bih[4] = {(const float*)d_in[7], (const float*)d_in[11], (const float*)d_in[15], (const float*)d_in[19]};
  const float* bhh[4] = {(const float*)d_in[8], (const float*)d_in[12], (const float*)d_in[16], (const float*)d_in[20]};
  const float* nl_w = (const float*)d_in[21];
  const float* nl_b = (const float*)d_in[22];
  const float* sc_w = (const float*)d_in[23];
  const float* sc_b = (const float*)d_in[24];
  float* out = (float*)d_out;

  float* ws = (float*)d_ws;
  size_t off = 0;
  float* levs = ws + off;   off += 32768;
  uint4* wqk[4];
  for (int l = 0; l < 4; ++l){ wqk[l] = (uint4*)(ws + off); off += 65536; }   // 256KB each
  float* sck[4];
  for (int l = 0; l < 4; ++l){ sck[l] = ws + off; off += 1024; }
  float* x0 = ws + off;     off += (size_t)26656*168;
  float* G  = ws + off;     off += (size_t)28672*1024;
  float* h0 = ws + off;     off += (size_t)26656*256;
  float* h1 = ws + off;     off += (size_t)26656*256;
  float* h2 = ws + off;     off += (size_t)26656*256;
  (void)ws_size; (void)in_sizes; (void)n_in; (void)out_size;

  levels_k<<<1, 64, 0, stream>>>(train, ism, levs);
  win_x_k<<<17493, 256, 0, stream>>>(train, levs, x0);
  win_out_k<<<2499, 256, 0, stream>>>(train, levs, out + 639744);
  for (int l = 0; l < 4; ++l)
    packq_k<<<4, 256, 0, stream>>>(whh[l], wqk[l], sck[l]);

  // layer 0 (d=1): 833 steps, 32 rows -> 32 WGs x 1 row
  proj_mfma<<<dim3(8,209), 256, 0, stream>>>(x0, wih[0], bih[0], bhh[0], G, 26656, 168, 1024, 0, 0);
  srecq_k<1><<<32, 1024, 0, stream>>>(wqk[0], sck[0], G, h0, nullptr, 833, 1, 32);
  // layer 1 (d=4): 209 steps, 128 rows -> 128 WGs x 1 row
  proj_mfma<<<dim3(8,209), 256, 0, stream>>>(h0, wih[1], bih[1], bhh[1], G, 26752, 256, 1024, 4, 0);
  srecq_k<1><<<128, 1024, 0, stream>>>(wqk[1], sck[1], G, h1, nullptr, 209, 4, 128);
  // layer 2 (d=16): 53 steps, 512 rows -> 256 WGs x 2 rows
  proj_mfma<<<dim3(8,212), 256, 0, stream>>>(h1, wih[2], bih[2], bhh[2], G, 27136, 256, 1024, 16, 0);
  srecq_k<2><<<256, 1024, 0, stream>>>(wqk[2], sck[2], G, h2, nullptr, 53, 16, 512);
  // layer 3 (d=64): 14 steps, 2048 rows -> 256 WGs x 8 rows; residual h1; out overwrites h2
  proj_mfma<<<dim3(8,224), 256, 0, stream>>>(h2, wih[3], bih[3], bhh[3], G, 28672, 256, 1024, 64, 0);
  srecq_k<8><<<256, 1024, 0, stream>>>(wqk[3], sck[3], G, h2, h1, 14, 64, 2048);
  // nonlinear dense: xt = tanh(xf @ nl_w.T + nl_b)  (reuse h0)
  proj_mfma<<<dim3(2,209), 256, 0, stream>>>(h2, nl_w, nl_b, nullptr, h0, 26656, 256, 256, 0, 1);
  // scoring head -> pred (first half of d_out)
  sc_head<<<3332, 256, 0, stream>>>(h0, sc_w, sc_b, out, 26656);
}

// Round 12
// 1991.683 us; speedup vs baseline: 3.3369x; 1.8047x over previous
//
#include <hip/hip_runtime.h>
#include <hip/hip_fp16.h>
#include <math.h>

#define TT 833          // output timesteps
#define GDIM 1024       // 4*H gates

typedef _Float16 f16x8 __attribute__((ext_vector_type(8)));
typedef float    f32x4 __attribute__((ext_vector_type(4)));

__device__ __forceinline__ float sigm(float x){ return 1.f/(1.f+expf(-x)); }

#if __has_builtin(__builtin_amdgcn_sdot4)
__device__ __forceinline__ int sdot4(unsigned a, unsigned b, int c){
  return __builtin_amdgcn_sdot4((int)a, (int)b, c, false);
}
#else
__device__ __forceinline__ int sdot4(unsigned a, unsigned b, int c){
  int ai = (int)a, bi = (int)b;
  c += ((ai<<24)>>24)*((bi<<24)>>24);
  c += ((ai<<16)>>24)*((bi<<16)>>24);
  c += ((ai<<8)>>24)*((bi<<8)>>24);
  c += (ai>>24)*(bi>>24);
  return c;
}
#endif

// ---------------- level smoothing scan ----------------
__global__ void levels_k(const float* __restrict__ train, const float* __restrict__ ism,
                         float* __restrict__ levs){
  int b = threadIdx.x;
  if (b >= 32) return;
  float a = 1.f/(1.f+expf(-ism[0]));
  const float* tr = train + b*1024;
  float* lv = levs + b*1024;
  float lev = fmaxf(tr[0], 0.1f);
  lv[0] = lev;
  for (int t = 1; t < 1024; ++t){
    lev = fmaxf(a*tr[t] + (1.f-a)*lev, 0.1f);
    lv[t] = lev;
  }
}

// ---------------- normalized input windows x0[t*32+b][168] ----------------
__global__ void win_x_k(const float* __restrict__ train, const float* __restrict__ levs,
                        float* __restrict__ x0){
  int idx = blockIdx.x*256 + threadIdx.x;   // exactly 833*32*168
  int i = idx % 168;
  int r = idx / 168;       // t*32+b
  int b = r & 31;
  int t = r >> 5;
  x0[idx] = train[b*1024 + t + i] / levs[b*1024 + t + 167];
}

// ---------------- out_win -> d_out second half ----------------
__global__ void win_out_k(const float* __restrict__ train, const float* __restrict__ levs,
                          float* __restrict__ ow){
  int idx = blockIdx.x*256 + threadIdx.x;   // exactly 833*32*24
  int o = idx % 24;
  int r = idx / 24;
  int b = r & 31;
  int t = r >> 5;
  ow[idx] = train[b*1024 + 168 + t + o] / levs[b*1024 + t + 167];
}

// ---------------- quantize whh[1024][256] fp32 -> int8 wq[k16][1024] (+ per-row scale) ----
__global__ void packq_k(const float* __restrict__ w, uint4* __restrict__ wq,
                        float* __restrict__ sc){
  int g = blockIdx.x*256 + threadIdx.x;   // 1024 rows over 4 blocks
  if (g >= 1024) return;
  const float* row = w + (size_t)g*256;
  float amax = 0.f;
  for (int k = 0; k < 256; ++k) amax = fmaxf(amax, fabsf(row[k]));
  amax = fmaxf(amax, 1e-20f);
  float s = amax/127.f, inv = 127.f/amax;
  sc[g] = s;
  for (int k16 = 0; k16 < 16; ++k16){
    union { uint4 u; signed char b[16]; } r;
    #pragma unroll
    for (int j = 0; j < 16; ++j){
      float q = rintf(row[k16*16 + j]*inv);
      q = fminf(fmaxf(q, -127.f), 127.f);
      r.b[j] = (signed char)q;
    }
    wq[(size_t)k16*1024 + g] = r.u;
  }
}

// ---------------- MFMA fp16 GEMM: C[m][n] = A[map(m)][:K] . W[n][:K] + b1 (+b2), opt tanh ----
// 128x128 tile, 4 waves (2x2), mfma_f32_16x16x32_f16, 4x4 frags/wave, BK=32.
__global__ __launch_bounds__(256) void proj_mfma(
    const float* __restrict__ A, const float* __restrict__ W,
    const float* __restrict__ b1, const float* __restrict__ b2,
    float* __restrict__ C, int Mout, int K, int N, int dil, int act)
{
  __shared__ _Float16 As[128*40];
  __shared__ _Float16 Bs[128*40];
  const int tid = threadIdx.x;
  const int lane = tid & 63;
  const int w = tid >> 6, wr = w >> 1, wc = w & 1;
  const int m0 = blockIdx.y << 7, n0 = blockIdx.x << 7;

  const int rowA = tid >> 1;
  int srcrow;
  {
    int m = m0 + rowA;
    if (dil == 0) srcrow = (m < Mout) ? m : -1;
    else {
      int rows = dil << 5;
      int j = m / rows;
      int q = m - j*rows;
      int t = j*dil + (q >> 5);
      srcrow = (t < TT) ? ((t << 5) + (q & 31)) : -1;
    }
  }
  const int halfsel = tid & 1;
  const int nrow = n0 + rowA;

  f32x4 acc[4][4];
  #pragma unroll
  for (int i = 0; i < 4; ++i)
    #pragma unroll
    for (int j = 0; j < 4; ++j) acc[i][j] = (f32x4){0.f,0.f,0.f,0.f};

  const int nkt = (K + 31) >> 5;
  for (int kt = 0; kt < nkt; ++kt){
    const int k0 = (kt << 5) + halfsel*16;
    {
      union { uint4 u[2]; _Float16 h[16]; } tmp;
      if (srcrow >= 0 && k0 + 16 <= K){
        const float* s = A + (size_t)srcrow*K + k0;
        #pragma unroll
        for (int j = 0; j < 4; ++j){
          float4 v = *reinterpret_cast<const float4*>(s + j*4);
          tmp.h[j*4+0]=(_Float16)v.x; tmp.h[j*4+1]=(_Float16)v.y;
          tmp.h[j*4+2]=(_Float16)v.z; tmp.h[j*4+3]=(_Float16)v.w;
        }
      } else {
        const float* s = (srcrow >= 0) ? A + (size_t)srcrow*K : nullptr;
        #pragma unroll
        for (int j = 0; j < 16; ++j){
          int kk = k0 + j;
          tmp.h[j] = (s && kk < K) ? (_Float16)s[kk] : (_Float16)0.f;
        }
      }
      uint4* dst = reinterpret_cast<uint4*>(&As[rowA*40 + halfsel*16]);
      dst[0] = tmp.u[0]; dst[1] = tmp.u[1];
    }
    {
      union { uint4 u[2]; _Float16 h[16]; } tmp;
      if (k0 + 16 <= K){
        const float* s = W + (size_t)nrow*K + k0;
        #pragma unroll
        for (int j = 0; j < 4; ++j){
          float4 v = *reinterpret_cast<const float4*>(s + j*4);
          tmp.h[j*4+0]=(_Float16)v.x; tmp.h[j*4+1]=(_Float16)v.y;
          tmp.h[j*4+2]=(_Float16)v.z; tmp.h[j*4+3]=(_Float16)v.w;
        }
      } else {
        const float* s = W + (size_t)nrow*K;
        #pragma unroll
        for (int j = 0; j < 16; ++j){
          int kk = k0 + j;
          tmp.h[j] = (kk < K) ? (_Float16)s[kk] : (_Float16)0.f;
        }
      }
      uint4* dst = reinterpret_cast<uint4*>(&Bs[rowA*40 + halfsel*16]);
      dst[0] = tmp.u[0]; dst[1] = tmp.u[1];
    }
    __syncthreads();
    {
      const int kg = lane >> 4, r16 = lane & 15;
      f16x8 af[4], bf[4];
      #pragma unroll
      for (int mi = 0; mi < 4; ++mi)
        af[mi] = *reinterpret_cast<const f16x8*>(&As[(wr*64 + mi*16 + r16)*40 + kg*8]);
      #pragma unroll
      for (int nj = 0; nj < 4; ++nj)
        bf[nj] = *reinterpret_cast<const f16x8*>(&Bs[(wc*64 + nj*16 + r16)*40 + kg*8]);
      #pragma unroll
      for (int mi = 0; mi < 4; ++mi)
        #pragma unroll
        for (int nj = 0; nj < 4; ++nj)
          acc[mi][nj] = __builtin_amdgcn_mfma_f32_16x16x32_f16(af[mi], bf[nj], acc[mi][nj], 0, 0, 0);
    }
    __syncthreads();
  }
  #pragma unroll
  for (int mi = 0; mi < 4; ++mi){
    #pragma unroll
    for (int p = 0; p < 4; ++p){
      int mrow = m0 + wr*64 + mi*16 + (lane >> 4)*4 + p;
      if (mrow >= Mout) continue;
      #pragma unroll
      for (int nj = 0; nj < 4; ++nj){
        int ncol = n0 + wc*64 + nj*16 + (lane & 15);
        float v = acc[mi][nj][p] + b1[ncol] + (b2 ? b2[ncol] : 0.f);
        if (act) v = tanhf(v);
        C[(size_t)mrow*N + ncol] = v;
      }
    }
  }
}

// ---------------- register-resident int8 sdot4 LSTM recurrence (NR<=2) ----------------
// r11 kernel with the weight stream replaced by a one-time load into 16 uint4 VGPRs
// (256 int8 = the thread's whole gate row). Per-step memory = Gin only (4KB/WG).
// Same numerics as r11 (int8 w x int8 h sdot4). Keep body lean: VGPR must stay <128
// (16 waves/CU); watch for spill (FETCH explosion — r5/r6 signature).
template<int NR>
__global__ __launch_bounds__(1024) void srecr_k(
    const uint4* __restrict__ wq, const float* __restrict__ scale,
    const float* __restrict__ Gin,
    float* __restrict__ out, const float* __restrict__ res,
    int nsteps, int d, int rowsTotal)
{
  __shared__ unsigned int hq[NR][64];     // h int8-packed, 4 per uint
  __shared__ float psum[NR][1024];
  __shared__ float cst[NR][256];
  const int tid = threadIdx.x;
  const int q0 = blockIdx.x*NR;
  const float sg = scale[tid]*(1.f/127.f);
  uint4 wr_[16];
  #pragma unroll
  for (int k = 0; k < 16; ++k) wr_[k] = wq[(size_t)k*1024 + tid];
  for (int e = tid; e < NR*64; e += 1024) (&hq[0][0])[e] = 0u;
  for (int e = tid; e < NR*256; e += 1024) (&cst[0][0])[e] = 0.f;
  __syncthreads();

  for (int step = 0; step < nsteps; ++step){
    float gin[NR];
    const float* gbase = Gin + ((size_t)step*rowsTotal + q0)*GDIM;
    #pragma unroll
    for (int rr = 0; rr < NR; ++rr) gin[rr] = gbase[rr*GDIM + tid];
    int acc[NR];
    #pragma unroll
    for (int rr = 0; rr < NR; ++rr) acc[rr] = 0;

    #pragma unroll
    for (int k16 = 0; k16 < 16; ++k16){
      uint4 w = wr_[k16];
      #pragma unroll
      for (int rr = 0; rr < NR; ++rr){
        uint4 h4 = *reinterpret_cast<const uint4*>(&hq[rr][4*k16]);
        acc[rr] = sdot4(w.x, h4.x, acc[rr]);
        acc[rr] = sdot4(w.y, h4.y, acc[rr]);
        acc[rr] = sdot4(w.z, h4.z, acc[rr]);
        acc[rr] = sdot4(w.w, h4.w, acc[rr]);
      }
    }
    #pragma unroll
    for (int rr = 0; rr < NR; ++rr) psum[rr][tid] = fmaf((float)acc[rr], sg, gin[rr]);
    __syncthreads();
    for (int e = tid; e < NR*256; e += 1024){
      int rr = e >> 8, j = e & 255;
      float iv = psum[rr][j];
      float fv = psum[rr][j + 256];
      float gv = psum[rr][j + 512];
      float ov = psum[rr][j + 768];
      float c = cst[rr][j];
      c = sigm(fv)*c + sigm(iv)*tanhf(gv);
      float h = sigm(ov)*tanhf(c);
      cst[rr][j] = c;
      int qh = (int)rintf(h*127.f);
      reinterpret_cast<signed char*>(&hq[rr][0])[j] = (signed char)qh;
      int q = q0 + rr;
      int tg = step*d + (q >> 5);
      if (tg < TT){
        size_t oi = ((size_t)tg*32 + (q & 31))*256 + j;
        out[oi] = res ? (h + res[oi]) : h;
      }
    }
    __syncthreads();
  }
}

// ---------------- streamed int8 sdot4 recurrence (NR=8; r11 known-good) ----------------
template<int NR>
__global__ __launch_bounds__(1024) void srecq_k(
    const uint4* __restrict__ wq, const float* __restrict__ scale,
    const float* __restrict__ Gin,
    float* __restrict__ out, const float* __restrict__ res,
    int nsteps, int d, int rowsTotal)
{
  __shared__ unsigned int hq[NR][64];
  __shared__ float psum[NR][1024];
  __shared__ float cst[NR][256];
  const int tid = threadIdx.x;
  const int q0 = blockIdx.x*NR;
  const float sg = scale[tid]*(1.f/127.f);
  for (int e = tid; e < NR*64; e += 1024) (&hq[0][0])[e] = 0u;
  for (int e = tid; e < NR*256; e += 1024) (&cst[0][0])[e] = 0.f;
  __syncthreads();

  for (int step = 0; step < nsteps; ++step){
    float gin[NR];
    const float* gbase = Gin + ((size_t)step*rowsTotal + q0)*GDIM;
    #pragma unroll
    for (int rr = 0; rr < NR; ++rr) gin[rr] = gbase[rr*GDIM + tid];
    int acc[NR];
    #pragma unroll
    for (int rr = 0; rr < NR; ++rr) acc[rr] = 0;

    #pragma unroll 4
    for (int k16 = 0; k16 < 16; ++k16){
      uint4 w = wq[(size_t)k16*1024 + tid];
      #pragma unroll
      for (int rr = 0; rr < NR; ++rr){
        uint4 h4 = *reinterpret_cast<const uint4*>(&hq[rr][4*k16]);
        acc[rr] = sdot4(w.x, h4.x, acc[rr]);
        acc[rr] = sdot4(w.y, h4.y, acc[rr]);
        acc[rr] = sdot4(w.z, h4.z, acc[rr]);
        acc[rr] = sdot4(w.w, h4.w, acc[rr]);
      }
    }
    #pragma unroll
    for (int rr = 0; rr < NR; ++rr) psum[rr][tid] = fmaf((float)acc[rr], sg, gin[rr]);
    __syncthreads();
    for (int e = tid; e < NR*256; e += 1024){
      int rr = e >> 8, j = e & 255;
      float iv = psum[rr][j];
      float fv = psum[rr][j + 256];
      float gv = psum[rr][j + 512];
      float ov = psum[rr][j + 768];
      float c = cst[rr][j];
      c = sigm(fv)*c + sigm(iv)*tanhf(gv);
      float h = sigm(ov)*tanhf(c);
      cst[rr][j] = c;
      int qh = (int)rintf(h*127.f);
      reinterpret_cast<signed char*>(&hq[rr][0])[j] = (signed char)qh;
      int q = q0 + rr;
      int tg = step*d + (q >> 5);
      if (tg < TT){
        size_t oi = ((size_t)tg*32 + (q & 31))*256 + j;
        out[oi] = res ? (h + res[oi]) : h;
      }
    }
    __syncthreads();
  }
}

// ---------------- scoring head: pred[m][24] = xt[m][:] . sc_w[n][:] + sc_b ----------------
__global__ __launch_bounds__(256) void sc_head(const float* __restrict__ xt, const float* __restrict__ w,
                        const float* __restrict__ bias, float* __restrict__ outp, int M){
  __shared__ float arow[8][256];
  int m0 = blockIdx.x << 3;
  int tid = threadIdx.x;
  #pragma unroll
  for (int i = 0; i < 8; ++i){
    int e = tid + (i << 8);
    int r = e >> 8, k = e & 255;
    arow[r][k] = (m0 + r < M) ? xt[(size_t)(m0 + r)*256 + k] : 0.f;
  }
  __syncthreads();
  int r = tid >> 5, n = tid & 31;
  if (n < 24 && (m0 + r) < M){
    float acc = bias[n];
    const float* wr = w + n*256;
    #pragma unroll 8
    for (int k = 0; k < 256; ++k) acc = fmaf(arow[r][k], wr[k], acc);
    outp[(size_t)(m0 + r)*24 + n] = acc;
  }
}

extern "C" void kernel_launch(void* const* d_in, const int* in_sizes, int n_in,
                              void* d_out, int out_size, void* d_ws, size_t ws_size,
                              hipStream_t stream){
  const float* train = (const float*)d_in[0];
  const float* ism   = (const float*)d_in[4];
  const float* wih[4] = {(const float*)d_in[5], (const float*)d_in[9], (const float*)d_in[13], (const float*)d_in[17]};
  const float* whh[4] = {(const float*)d_in[6], (const float*)d_in[10], (const float*)d_in[14], (const float*)d_in[18]};
  const float* bih[4] = {(const float*)d_in[7], (const float*)d_in[11], (const float*)d_in[15], (const float*)d_in[19]};
  const float* bhh[4] = {(const float*)d_in[8], (const float*)d_in[12], (const float*)d_in[16], (const float*)d_in[20]};
  const float* nl_w = (const float*)d_in[21];
  const float* nl_b = (const float*)d_in[22];
  const float* sc_w = (const float*)d_in[23];
  const float* sc_b = (const float*)d_in[24];
  float* out = (float*)d_out;

  float* ws = (float*)d_ws;
  size_t off = 0;
  float* levs = ws + off;   off += 32768;
  uint4* wqk[4];
  for (int l = 0; l < 4; ++l){ wqk[l] = (uint4*)(ws + off); off += 65536; }   // 256KB each
  float* sck[4];
  for (int l = 0; l < 4; ++l){ sck[l] = ws + off; off += 1024; }
  float* x0 = ws + off;     off += (size_t)26656*168;
  float* G  = ws + off;     off += (size_t)28672*1024;
  float* h0 = ws + off;     off += (size_t)26656*256;
  float* h1 = ws + off;     off += (size_t)26656*256;
  float* h2 = ws + off;     off += (size_t)26656*256;
  (void)ws_size; (void)in_sizes; (void)n_in; (void)out_size;

  levels_k<<<1, 64, 0, stream>>>(train, ism, levs);
  win_x_k<<<17493, 256, 0, stream>>>(train, levs, x0);
  win_out_k<<<2499, 256, 0, stream>>>(train, levs, out + 639744);
  for (int l = 0; l < 4; ++l)
    packq_k<<<4, 256, 0, stream>>>(whh[l], wqk[l], sck[l]);

  // layer 0 (d=1): 833 steps, 32 rows -> 32 WGs x 1 row (register-resident weights)
  proj_mfma<<<dim3(8,209), 256, 0, stream>>>(x0, wih[0], bih[0], bhh[0], G, 26656, 168, 1024, 0, 0);
  srecr_k<1><<<32, 1024, 0, stream>>>(wqk[0], sck[0], G, h0, nullptr, 833, 1, 32);
  // layer 1 (d=4): 209 steps, 128 rows -> 128 WGs x 1 row
  proj_mfma<<<dim3(8,209), 256, 0, stream>>>(h0, wih[1], bih[1], bhh[1], G, 26752, 256, 1024, 4, 0);
  srecr_k<1><<<128, 1024, 0, stream>>>(wqk[1], sck[1], G, h1, nullptr, 209, 4, 128);
  // layer 2 (d=16): 53 steps, 512 rows -> 256 WGs x 2 rows
  proj_mfma<<<dim3(8,212), 256, 0, stream>>>(h1, wih[2], bih[2], bhh[2], G, 27136, 256, 1024, 16, 0);
  srecr_k<2><<<256, 1024, 0, stream>>>(wqk[2], sck[2], G, h2, nullptr, 53, 16, 512);
  // layer 3 (d=64): 14 steps, 2048 rows -> 256 WGs x 8 rows; residual h1; out overwrites h2
  proj_mfma<<<dim3(8,224), 256, 0, stream>>>(h2, wih[3], bih[3], bhh[3], G, 28672, 256, 1024, 64, 0);
  srecq_k<8><<<256, 1024, 0, stream>>>(wqk[3], sck[3], G, h2, h1, 14, 64, 2048);
  // nonlinear dense: xt = tanh(xf @ nl_w.T + nl_b)  (reuse h0)
  proj_mfma<<<dim3(2,209), 256, 0, stream>>>(h2, nl_w, nl_b, nullptr, h0, 26656, 256, 256, 0, 1);
  // scoring head -> pred (first half of d_out)
  sc_head<<<3332, 256, 0, stream>>>(h0, sc_w, sc_b, out, 26656);
}